// Round 4
// baseline (1158.751 us; speedup 1.0000x reference)
//
#include <hip/hip_runtime.h>

typedef unsigned short u16;
typedef __attribute__((ext_vector_type(8))) short bf16x8;
typedef __attribute__((ext_vector_type(4))) float f32x4;

union U8 { unsigned int w[4]; bf16x8 v; };

#define LEAKY 0.2f
#define LN_EPS 1e-5f
#define NTILES 20000   // 640000 edges / 32 per wave-tile
#define NWAVES 4096    // 256 blocks x 16 waves

// fp32 -> bf16 RTNE
__device__ __forceinline__ u16 f2bf(float f) {
  union { float f; unsigned int u; } a; a.f = f;
  unsigned int u = a.u;
  return (u16)((u + 0x7fffu + ((u >> 16) & 1u)) >> 16);
}
__device__ __forceinline__ unsigned int pk2(float lo, float hi) {
  return (unsigned int)f2bf(lo) | ((unsigned int)f2bf(hi) << 16);
}

// Build the 128KB weight fragment image in ws, in EXACT per-MFMA fragment
// order: frag f (0..127) is a 1KB block; within it lane l (0..63) holds 8
// contiguous bf16 (16B -> one conflict-free ds_read_b128).
// f = base + c*8 + n;  bases: W1=0 (c 0..7), W2=64 (c 0..3), W3=96 (c 0..3).
// Element (f, l, i):  p=l&15, q=l>>4, j=i&3, h=i>>2 ->
//   W[16n+p][32c + 4q + j + 16h]     (torch [out][in] row-major)
__global__ void build_wfrag(const float* __restrict__ W1,
                            const float* __restrict__ W2,
                            const float* __restrict__ W3,
                            u16* __restrict__ wout) {
  int id = blockIdx.x * 256 + threadIdx.x;     // 0..65535
  int f = id >> 9, l = (id >> 3) & 63, i = id & 7;
  int p = l & 15, q = l >> 4, j = i & 3, h = i >> 2;
  const float* W; int c, K;
  if (f < 64)      { W = W1; c = f >> 3;        K = 256; }
  else if (f < 96) { W = W2; c = (f - 64) >> 3; K = 128; }
  else             { W = W3; c = (f - 96) >> 3; K = 128; }
  int n = f & 7;
  wout[id] = f2bf(W[(16 * n + p) * K + 32 * c + 4 * q + j + 16 * h]);
}

// gather one edge's [x[dest] | x[src]] row (per-lane slice) into 8 bf16 frags
// xr0/xr1 already include +4q float offset
__device__ __forceinline__ void gather16(const float* __restrict__ xr0,
                                         const float* __restrict__ xr1,
                                         U8* mf) {
  float4 g[16];
  const float4* a = (const float4*)xr0;
  const float4* b = (const float4*)xr1;
  #pragma unroll
  for (int c = 0; c < 4; ++c) {
    g[2 * c]     = a[8 * c];
    g[2 * c + 1] = a[8 * c + 4];
    g[8 + 2 * c] = b[8 * c];
    g[9 + 2 * c] = b[8 * c + 4];
  }
  #pragma unroll
  for (int c = 0; c < 8; ++c) {
    mf[c].w[0] = pk2(g[2 * c].x,     g[2 * c].y);
    mf[c].w[1] = pk2(g[2 * c].z,     g[2 * c].w);
    mf[c].w[2] = pk2(g[2 * c + 1].x, g[2 * c + 1].y);
    mf[c].w[3] = pk2(g[2 * c + 1].z, g[2 * c + 1].w);
  }
}

// leaky-relu acc in place, then pack to bf16 B-frags for the next layer:
// frag c2 elem i  <->  chan 32c2 + 4q + (i&3) + 16(i>>2)  = acc[2c2+(i>>2)][i&3]
__device__ __forceinline__ void leaky_pack(f32x4* acc, U8* hf) {
  #pragma unroll
  for (int n = 0; n < 8; ++n) {
    #pragma unroll
    for (int j = 0; j < 4; ++j) {
      float v = acc[n][j];
      acc[n][j] = (v >= 0.f) ? v : LEAKY * v;
    }
  }
  #pragma unroll
  for (int c = 0; c < 4; ++c) {
    hf[c].w[0] = pk2(acc[2 * c][0],     acc[2 * c][1]);
    hf[c].w[1] = pk2(acc[2 * c][2],     acc[2 * c][3]);
    hf[c].w[2] = pk2(acc[2 * c + 1][0], acc[2 * c + 1][1]);
    hf[c].w[3] = pk2(acc[2 * c + 1][2], acc[2 * c + 1][3]);
  }
}

// one layer: B-frag (W) read once from LDS, used for BOTH row tiles
template <int FBASE, int NC>
__device__ __forceinline__ void gemm(const u16* __restrict__ wlds, int lane,
                                     const U8* mfA, const U8* mfB,
                                     f32x4* accA, f32x4* accB) {
  #pragma unroll
  for (int c = 0; c < NC; ++c) {
    #pragma unroll
    for (int n = 0; n < 8; ++n) {
      U8 wf;
      wf.v = *(const bf16x8*)(wlds + ((FBASE + c * 8 + n) << 9) + (lane << 3));
      accA[n] = __builtin_amdgcn_mfma_f32_16x16x32_bf16(wf.v, mfA[c].v, accA[n], 0, 0, 0);
      accB[n] = __builtin_amdgcn_mfma_f32_16x16x32_bf16(wf.v, mfB[c].v, accB[n], 0, 0, 0);
    }
  }
}

// LayerNorm one 16-edge tile held as acc[n][j] = h[edge p][chan 16n+4q+j]
// Plain stores: the 64B-per-line lane pattern merges to full lines in L2
// (round-1 evidence: WRITE_SIZE == output bytes exactly). NT stores do NOT
// merge -> 2.1x write amplification + RMW fetch (round-3 evidence).
__device__ __forceinline__ void ln_store(const f32x4* acc, const f32x4* par,
                                         int q, float* __restrict__ orow) {
  float s = 0.f, ss = 0.f;
  #pragma unroll
  for (int n = 0; n < 8; ++n) {
    #pragma unroll
    for (int j = 0; j < 4; ++j) { float v = acc[n][j]; s += v; ss += v * v; }
  }
  s += __shfl_xor(s, 16, 64);  ss += __shfl_xor(ss, 16, 64);
  s += __shfl_xor(s, 32, 64);  ss += __shfl_xor(ss, 32, 64);
  float mean = s * (1.f / 128.f);
  float var  = ss * (1.f / 128.f) - mean * mean;
  float inv  = rsqrtf(var + LN_EPS);
  f32x4* o4 = (f32x4*)orow;
  #pragma unroll
  for (int n = 0; n < 8; ++n) {
    f32x4 gm = par[(n * 4 + q) * 4 + 2];
    f32x4 bt = par[(n * 4 + q) * 4 + 3];
    f32x4 r;
    r[0] = (acc[n][0] - mean) * inv * gm[0] + bt[0];
    r[1] = (acc[n][1] - mean) * inv * gm[1] + bt[1];
    r[2] = (acc[n][2] - mean) * inv * gm[2] + bt[2];
    r[3] = (acc[n][3] - mean) * inv * gm[3] + bt[3];
    o4[4 * n] = r;
  }
}

__global__ __launch_bounds__(1024, 4) void edge_mlp(
    const float* __restrict__ x, const int* __restrict__ ei,
    const float* __restrict__ b1, const float* __restrict__ b2,
    const float* __restrict__ gamma, const float* __restrict__ beta,
    const u16* __restrict__ wbf, float* __restrict__ out, int E) {

  __shared__ __align__(16) u16 wlds[65536];   // 128 KB weight frags
  __shared__ __align__(16) float wpar[512];   // b1|b2|gamma|beta frag table

  const int tid = threadIdx.x;
  // stage all weights once (persistent block, 16 waves behind 130KB LDS)
  {
    const uint4* s = (const uint4*)wbf;
    uint4* d = (uint4*)wlds;
    #pragma unroll
    for (int i = 0; i < 8; ++i) d[tid + i * 1024] = s[tid + i * 1024];
  }
  if (tid < 512) {
    int n = tid >> 6, q = (tid >> 4) & 3, prm = (tid >> 2) & 3, j = tid & 3;
    int col = 16 * n + 4 * q + j;
    const float* src = (prm == 0) ? b1 : (prm == 1) ? b2 : (prm == 2) ? gamma : beta;
    wpar[tid] = src[col];
  }
  __syncthreads();
  // no further barriers: each wave is fully independent

  const int lane = tid & 63;
  const int p = lane & 15, q = lane >> 4;
  const int wid = (blockIdx.x << 4) | (tid >> 6);
  const f32x4* par = (const f32x4*)wpar;   // cell index (n*4+q)*4 + prm

  for (int t = wid; t < NTILES; t += NWAVES) {
    const int e0 = t * 32;
    const long nd0 = ei[E + e0 + p],      ns0 = ei[e0 + p];
    const long nd1 = ei[E + e0 + 16 + p], ns1 = ei[e0 + 16 + p];

    U8 mfA[8], mfB[8];
    gather16(x + nd0 * 128 + 4 * q, x + ns0 * 128 + 4 * q, mfA);
    gather16(x + nd1 * 128 + 4 * q, x + ns1 * 128 + 4 * q, mfB);

    f32x4 accA[8], accB[8];
    // ---- GEMM1: acc init = b1, K=256 (c 0..7) ----
    #pragma unroll
    for (int n = 0; n < 8; ++n) {
      f32x4 b = par[(n * 4 + q) * 4 + 0];
      accA[n] = b; accB[n] = b;
    }
    gemm<0, 8>(wlds, lane, mfA, mfB, accA, accB);
    U8 hfA[4], hfB[4];
    leaky_pack(accA, hfA);
    leaky_pack(accB, hfB);

    // ---- GEMM2: init = b2, K=128 (c 0..3) ----
    #pragma unroll
    for (int n = 0; n < 8; ++n) {
      f32x4 b = par[(n * 4 + q) * 4 + 1];
      accA[n] = b; accB[n] = b;
    }
    gemm<64, 4>(wlds, lane, hfA, hfB, accA, accB);
    leaky_pack(accA, hfA);
    leaky_pack(accB, hfB);

    // ---- GEMM3: no bias, K=128 ----
    #pragma unroll
    for (int n = 0; n < 8; ++n) { accA[n] = (f32x4)(0.f); accB[n] = (f32x4)(0.f); }
    gemm<96, 4>(wlds, lane, hfA, hfB, accA, accB);

    // ---- LayerNorm + store ----
    ln_store(accA, par, q, out + (long)(e0 + p) * 128 + 4 * q);
    ln_store(accB, par, q, out + (long)(e0 + 16 + p) * 128 + 4 * q);
  }
}

extern "C" void kernel_launch(void* const* d_in, const int* in_sizes, int n_in,
                              void* d_out, int out_size, void* d_ws, size_t ws_size,
                              hipStream_t stream) {
  const float* x     = (const float*)d_in[0];
  const int*   ei    = (const int*)d_in[1];
  const float* W1    = (const float*)d_in[2];
  const float* b1    = (const float*)d_in[3];
  const float* W2    = (const float*)d_in[4];
  const float* b2    = (const float*)d_in[5];
  const float* W3    = (const float*)d_in[6];
  const float* gamma = (const float*)d_in[7];
  const float* beta  = (const float*)d_in[8];
  const int E = in_sizes[1] / 2;   // 640000
  u16* wbf = (u16*)d_ws;           // 128 KB fragment image

  build_wfrag<<<256, 256, 0, stream>>>(W1, W2, W3, wbf);
  edge_mlp<<<256, 1024, 0, stream>>>(x, ei, b1, b2, gamma, beta, wbf,
                                     (float*)d_out, E);
}

// Round 5
// 778.206 us; speedup vs baseline: 1.4890x; 1.4890x over previous
//
#include <hip/hip_runtime.h>

typedef unsigned short u16;
typedef __attribute__((ext_vector_type(8))) short bf16x8;
typedef __attribute__((ext_vector_type(4))) float f32x4;

union U8 { unsigned int w[4]; bf16x8 v; };

#define LEAKY 0.2f
#define LN_EPS 1e-5f
#define NTILES 20000   // 640000 edges / 32 per wave-tile
#define NWAVES 2048    // 256 blocks x 8 waves

// fp32 -> bf16 RTNE
__device__ __forceinline__ u16 f2bf(float f) {
  union { float f; unsigned int u; } a; a.f = f;
  unsigned int u = a.u;
  return (u16)((u + 0x7fffu + ((u >> 16) & 1u)) >> 16);
}
__device__ __forceinline__ unsigned int pk2(float lo, float hi) {
  return (unsigned int)f2bf(lo) | ((unsigned int)f2bf(hi) << 16);
}

// Build the 128KB weight fragment image in ws, in EXACT per-MFMA fragment
// order: frag f (0..127) is a 1KB block; within it lane l (0..63) holds 8
// contiguous bf16 (16B -> one conflict-free ds_read_b128).
// f = base + c*8 + n;  bases: W1=0 (c 0..7), W2=64 (c 0..3), W3=96 (c 0..3).
// Element (f, l, i):  p=l&15, q=l>>4, j=i&3, h=i>>2 ->
//   W[16n+p][32c + 4q + j + 16h]     (torch [out][in] row-major)
__global__ void build_wfrag(const float* __restrict__ W1,
                            const float* __restrict__ W2,
                            const float* __restrict__ W3,
                            u16* __restrict__ wout) {
  int id = blockIdx.x * 256 + threadIdx.x;     // 0..65535
  int f = id >> 9, l = (id >> 3) & 63, i = id & 7;
  int p = l & 15, q = l >> 4, j = i & 3, h = i >> 2;
  const float* W; int c, K;
  if (f < 64)      { W = W1; c = f >> 3;        K = 256; }
  else if (f < 96) { W = W2; c = (f - 64) >> 3; K = 128; }
  else             { W = W3; c = (f - 96) >> 3; K = 128; }
  int n = f & 7;
  wout[id] = f2bf(W[(16 * n + p) * K + 32 * c + 4 * q + j + 16 * h]);
}

// gather one edge's [x[dest] | x[src]] row (per-lane slice) into 8 bf16 frags
// xr0/xr1 already include +4q float offset
__device__ __forceinline__ void gather16(const float* __restrict__ xr0,
                                         const float* __restrict__ xr1,
                                         U8* mf) {
  float4 g[16];
  const float4* a = (const float4*)xr0;
  const float4* b = (const float4*)xr1;
  #pragma unroll
  for (int c = 0; c < 4; ++c) {
    g[2 * c]     = a[8 * c];
    g[2 * c + 1] = a[8 * c + 4];
    g[8 + 2 * c] = b[8 * c];
    g[9 + 2 * c] = b[8 * c + 4];
  }
  #pragma unroll
  for (int c = 0; c < 8; ++c) {
    mf[c].w[0] = pk2(g[2 * c].x,     g[2 * c].y);
    mf[c].w[1] = pk2(g[2 * c].z,     g[2 * c].w);
    mf[c].w[2] = pk2(g[2 * c + 1].x, g[2 * c + 1].y);
    mf[c].w[3] = pk2(g[2 * c + 1].z, g[2 * c + 1].w);
  }
}

// leaky-relu acc in place, then pack to bf16 B-frags for the next layer:
// frag c2 elem i  <->  chan 32c2 + 4q + (i&3) + 16(i>>2)  = acc[2c2+(i>>2)][i&3]
__device__ __forceinline__ void leaky_pack(f32x4* acc, U8* hf) {
  #pragma unroll
  for (int n = 0; n < 8; ++n) {
    #pragma unroll
    for (int j = 0; j < 4; ++j) {
      float v = acc[n][j];
      acc[n][j] = (v >= 0.f) ? v : LEAKY * v;
    }
  }
  #pragma unroll
  for (int c = 0; c < 4; ++c) {
    hf[c].w[0] = pk2(acc[2 * c][0],     acc[2 * c][1]);
    hf[c].w[1] = pk2(acc[2 * c][2],     acc[2 * c][3]);
    hf[c].w[2] = pk2(acc[2 * c + 1][0], acc[2 * c + 1][1]);
    hf[c].w[3] = pk2(acc[2 * c + 1][2], acc[2 * c + 1][3]);
  }
}

// one layer: B-frag (W) read once from LDS, used for BOTH row tiles
template <int FBASE, int NC>
__device__ __forceinline__ void gemm(const u16* __restrict__ wlds, int lane,
                                     const U8* mfA, const U8* mfB,
                                     f32x4* accA, f32x4* accB) {
  #pragma unroll
  for (int c = 0; c < NC; ++c) {
    #pragma unroll
    for (int n = 0; n < 8; ++n) {
      U8 wf;
      wf.v = *(const bf16x8*)(wlds + ((FBASE + c * 8 + n) << 9) + (lane << 3));
      accA[n] = __builtin_amdgcn_mfma_f32_16x16x32_bf16(wf.v, mfA[c].v, accA[n], 0, 0, 0);
      accB[n] = __builtin_amdgcn_mfma_f32_16x16x32_bf16(wf.v, mfB[c].v, accB[n], 0, 0, 0);
    }
  }
}

// LayerNorm one 16-edge tile held as acc[n][j] = h[edge p][chan 16n+4q+j]
// Plain stores: this lane pattern merges to full lines in L2 (round-1
// evidence: WRITE_SIZE == output bytes). NT stores don't merge (round 3).
__device__ __forceinline__ void ln_store(const f32x4* acc, const f32x4* par,
                                         int q, float* __restrict__ orow) {
  float s = 0.f, ss = 0.f;
  #pragma unroll
  for (int n = 0; n < 8; ++n) {
    #pragma unroll
    for (int j = 0; j < 4; ++j) { float v = acc[n][j]; s += v; ss += v * v; }
  }
  s += __shfl_xor(s, 16, 64);  ss += __shfl_xor(ss, 16, 64);
  s += __shfl_xor(s, 32, 64);  ss += __shfl_xor(ss, 32, 64);
  float mean = s * (1.f / 128.f);
  float var  = ss * (1.f / 128.f) - mean * mean;
  float inv  = rsqrtf(var + LN_EPS);
  f32x4* o4 = (f32x4*)orow;
  #pragma unroll
  for (int n = 0; n < 8; ++n) {
    f32x4 gm = par[(n * 4 + q) * 4 + 2];
    f32x4 bt = par[(n * 4 + q) * 4 + 3];
    f32x4 r;
    r[0] = (acc[n][0] - mean) * inv * gm[0] + bt[0];
    r[1] = (acc[n][1] - mean) * inv * gm[1] + bt[1];
    r[2] = (acc[n][2] - mean) * inv * gm[2] + bt[2];
    r[3] = (acc[n][3] - mean) * inv * gm[3] + bt[3];
    o4[4 * n] = r;
  }
}

// NOTE: (512,2) is load-bearing. Unified VGPR+AGPR need is ~190/wave; any
// tighter bound (round 4: cap 128) spills ~64 regs -> +2GB scratch traffic.
__global__ __launch_bounds__(512, 2) void edge_mlp(
    const float* __restrict__ x, const int* __restrict__ ei,
    const float* __restrict__ b1, const float* __restrict__ b2,
    const float* __restrict__ gamma, const float* __restrict__ beta,
    const u16* __restrict__ wbf, float* __restrict__ out, int E) {

  __shared__ __align__(16) u16 wlds[65536];   // 128 KB weight frags
  __shared__ __align__(16) float wpar[512];   // b1|b2|gamma|beta frag table

  const int tid = threadIdx.x;
  // stage all weights once (persistent block)
  {
    const uint4* s = (const uint4*)wbf;
    uint4* d = (uint4*)wlds;
    #pragma unroll
    for (int i = 0; i < 16; ++i) d[tid + i * 512] = s[tid + i * 512];
  }
  if (tid < 512) {
    int n = tid >> 6, q = (tid >> 4) & 3, prm = (tid >> 2) & 3, j = tid & 3;
    int col = 16 * n + 4 * q + j;
    const float* src = (prm == 0) ? b1 : (prm == 1) ? b2 : (prm == 2) ? gamma : beta;
    wpar[tid] = src[col];
  }
  __syncthreads();
  // no further barriers: each wave is fully independent

  const int lane = tid & 63;
  const int p = lane & 15, q = lane >> 4;
  const int wid = (blockIdx.x << 3) | (tid >> 6);
  const f32x4* par = (const f32x4*)wpar;   // cell index (n*4+q)*4 + prm

  int t = wid;
  int nd0, ns0, nd1, ns1;
  if (t < NTILES) {
    const int e0 = t * 32;
    nd0 = ei[E + e0 + p];      ns0 = ei[e0 + p];
    nd1 = ei[E + e0 + 16 + p]; ns1 = ei[e0 + 16 + p];
  }

  for (; t < NTILES; t += NWAVES) {
    const int e0 = t * 32;

    U8 mfA[8], mfB[8];
    gather16(x + (long)nd0 * 128 + 4 * q, x + (long)ns0 * 128 + 4 * q, mfA);
    gather16(x + (long)nd1 * 128 + 4 * q, x + (long)ns1 * 128 + 4 * q, mfB);

    // prefetch next tile's indices; GEMMs below cover the latency
    {
      const int tn = (t + NWAVES < NTILES) ? t + NWAVES : t;
      const int e0n = tn * 32;
      nd0 = ei[E + e0n + p];      ns0 = ei[e0n + p];
      nd1 = ei[E + e0n + 16 + p]; ns1 = ei[e0n + 16 + p];
    }

    f32x4 accA[8], accB[8];
    // ---- GEMM1: acc init = b1, K=256 (c 0..7) ----
    #pragma unroll
    for (int n = 0; n < 8; ++n) {
      f32x4 b = par[(n * 4 + q) * 4 + 0];
      accA[n] = b; accB[n] = b;
    }
    gemm<0, 8>(wlds, lane, mfA, mfB, accA, accB);
    U8 hfA[4], hfB[4];
    leaky_pack(accA, hfA);
    leaky_pack(accB, hfB);

    // ---- GEMM2: init = b2, K=128 (c 0..3) ----
    #pragma unroll
    for (int n = 0; n < 8; ++n) {
      f32x4 b = par[(n * 4 + q) * 4 + 1];
      accA[n] = b; accB[n] = b;
    }
    gemm<64, 4>(wlds, lane, hfA, hfB, accA, accB);
    leaky_pack(accA, hfA);
    leaky_pack(accB, hfB);

    // ---- GEMM3: no bias, K=128 ----
    #pragma unroll
    for (int n = 0; n < 8; ++n) { accA[n] = (f32x4)(0.f); accB[n] = (f32x4)(0.f); }
    gemm<96, 4>(wlds, lane, hfA, hfB, accA, accB);

    // ---- LayerNorm + store ----
    ln_store(accA, par, q, out + (long)(e0 + p) * 128 + 4 * q);
    ln_store(accB, par, q, out + (long)(e0 + 16 + p) * 128 + 4 * q);
  }
}

extern "C" void kernel_launch(void* const* d_in, const int* in_sizes, int n_in,
                              void* d_out, int out_size, void* d_ws, size_t ws_size,
                              hipStream_t stream) {
  const float* x     = (const float*)d_in[0];
  const int*   ei    = (const int*)d_in[1];
  const float* W1    = (const float*)d_in[2];
  const float* b1    = (const float*)d_in[3];
  const float* W2    = (const float*)d_in[4];
  const float* b2    = (const float*)d_in[5];
  const float* W3    = (const float*)d_in[6];
  const float* gamma = (const float*)d_in[7];
  const float* beta  = (const float*)d_in[8];
  const int E = in_sizes[1] / 2;   // 640000
  u16* wbf = (u16*)d_ws;           // 128 KB fragment image

  build_wfrag<<<256, 256, 0, stream>>>(W1, W2, W3, wbf);
  edge_mlp<<<256, 512, 0, stream>>>(x, ei, b1, b2, gamma, beta, wbf,
                                    (float*)d_out, E);
}

// Round 7
// 400.064 us; speedup vs baseline: 2.8964x; 1.9452x over previous
//
#include <hip/hip_runtime.h>

typedef unsigned short u16;
typedef unsigned int u32;
typedef __attribute__((ext_vector_type(8))) short bf16x8;
typedef __attribute__((ext_vector_type(4))) float f32x4;
typedef __attribute__((ext_vector_type(4))) u32 u32x4;

union U8 { u32 w[4]; u32x4 u4; bf16x8 v; };

#define LEAKY 0.2f
#define LN_EPS 1e-5f

// fp32 -> bf16 RTNE (bit math — proven rounds 1-5; do NOT use v_cvt_pk asm,
// round 6 showed it poisons the packed word -> NaN)
__device__ __forceinline__ u16 f2bf(float f) {
  union { float f; u32 u; } a; a.f = f;
  return (u16)((a.u + 0x7fffu + ((a.u >> 16) & 1u)) >> 16);
}
__device__ __forceinline__ u32 pk2(float lo, float hi) {
  return (u32)f2bf(lo) | ((u32)f2bf(hi) << 16);
}

// pack two f32x4 accs (8 elems, i = j + 4h) into one u32x4 bf16 fragment word
__device__ __forceinline__ u32x4 pack8(const f32x4& a, const f32x4& b) {
  u32x4 r;
  r[0] = pk2(a[0], a[1]); r[1] = pk2(a[2], a[3]);
  r[2] = pk2(b[0], b[1]); r[3] = pk2(b[2], b[3]);
  return r;
}

// Build 128KB weight fragment image (128 frags x 1KB). frag f: lane l holds 8
// contiguous bf16 (one conflict-free ds_read_b128 at f*1024 + l*16).
// f = base + c*8 + n; W1: f 0..63 (c 0..3 = W1a/dest cols, c 4..7 = W1b/src
// cols); W2: f 64..95; W3: f 96..127.
// Element (f,l,i): p=l&15, q=l>>4, j=i&3, h=i>>2 -> W[16n+p][32c+4q+j+16h]
__global__ void build_wfrag(const float* __restrict__ W1,
                            const float* __restrict__ W2,
                            const float* __restrict__ W3,
                            u16* __restrict__ wout) {
  int id = blockIdx.x * 256 + threadIdx.x;     // 0..65535
  int f = id >> 9, l = (id >> 3) & 63, i = id & 7;
  int p = l & 15, q = l >> 4, j = i & 3, h = i >> 2;
  const float* W; int c, K;
  if (f < 64)      { W = W1; c = f >> 3;        K = 256; }
  else if (f < 96) { W = W2; c = (f - 64) >> 3; K = 128; }
  else             { W = W3; c = (f - 96) >> 3; K = 128; }
  int n = f & 7;
  wout[id] = f2bf(W[(16 * n + p) * K + 32 * c + 4 * q + j + 16 * h]);
}

// one layer vs a staged frag window: frag f = FBASE + c*8 + n
template <int FBASE, int NC>
__device__ __forceinline__ void gemm(const u16* __restrict__ wlds, int lane,
                                     const U8* mfA, const U8* mfB,
                                     f32x4* accA, f32x4* accB) {
  #pragma unroll
  for (int c = 0; c < NC; ++c) {
    #pragma unroll
    for (int n = 0; n < 8; ++n) {
      U8 wf;
      wf.v = *(const bf16x8*)(wlds + ((FBASE + c * 8 + n) << 9) + (lane << 3));
      accA[n] = __builtin_amdgcn_mfma_f32_16x16x32_bf16(wf.v, mfA[c].v, accA[n], 0, 0, 0);
      accB[n] = __builtin_amdgcn_mfma_f32_16x16x32_bf16(wf.v, mfB[c].v, accB[n], 0, 0, 0);
    }
  }
}

// leaky (= max(v, 0.2v)) in place, then pack to next layer's bf16 frags
__device__ __forceinline__ void leaky_pack(f32x4* acc, U8* hf) {
  #pragma unroll
  for (int n = 0; n < 8; ++n) {
    #pragma unroll
    for (int j = 0; j < 4; ++j) {
      float v = acc[n][j];
      acc[n][j] = fmaxf(v, LEAKY * v);
    }
  }
  #pragma unroll
  for (int c = 0; c < 4; ++c) hf[c].u4 = pack8(acc[2 * c], acc[2 * c + 1]);
}

// h1 frag word: leaky(bf16(ya)+bf16(yb)) on a packed pair
__device__ __forceinline__ u32 addleaky(u32 ua, u32 ub) {
  float alo = __uint_as_float(ua << 16);
  float ahi = __uint_as_float(ua & 0xFFFF0000u);
  float blo = __uint_as_float(ub << 16);
  float bhi = __uint_as_float(ub & 0xFFFF0000u);
  float lo = alo + blo, hi = ahi + bhi;
  lo = fmaxf(lo, LEAKY * lo);
  hi = fmaxf(hi, LEAKY * hi);
  return pk2(lo, hi);
}

// LayerNorm one 16-edge tile: acc[n][j] = h[edge p][chan 16n+4q+j]
__device__ __forceinline__ void ln_store(const f32x4* acc, const f32x4* gmf,
                                         const f32x4* btf, int q,
                                         float* __restrict__ orow) {
  float s = 0.f, ss = 0.f;
  #pragma unroll
  for (int n = 0; n < 8; ++n) {
    #pragma unroll
    for (int j = 0; j < 4; ++j) { float v = acc[n][j]; s += v; ss += v * v; }
  }
  s += __shfl_xor(s, 16, 64);  ss += __shfl_xor(ss, 16, 64);
  s += __shfl_xor(s, 32, 64);  ss += __shfl_xor(ss, 32, 64);
  float mean = s * (1.f / 128.f);
  float var  = fmaxf(ss * (1.f / 128.f) - mean * mean, 0.f);
  float inv  = rsqrtf(var + LN_EPS);
  f32x4* o4 = (f32x4*)orow;
  #pragma unroll
  for (int n = 0; n < 8; ++n) {
    f32x4 gm = gmf[4 * n + q], bt = btf[4 * n + q];
    f32x4 r;
    r[0] = (acc[n][0] - mean) * inv * gm[0] + bt[0];
    r[1] = (acc[n][1] - mean) * inv * gm[1] + bt[1];
    r[2] = (acc[n][2] - mean) * inv * gm[2] + bt[2];
    r[3] = (acc[n][3] - mean) * inv * gm[3] + bt[3];
    o4[4 * n] = r;
  }
}

// ---- node precompute: y[n] = [ bf16(x[n]@W1a^T) | bf16(x[n]@W1b^T + b1) ]
// stored in fragment order: elem (c, q, i=j+4h) at u16 offset c*32 + q*8 + i
__global__ __launch_bounds__(512, 2) void node_pre(
    const float* __restrict__ x, const float* __restrict__ b1,
    const u16* __restrict__ wbf, u16* __restrict__ y, int NN) {
  __shared__ __align__(16) u16 wlds[32768];   // W1 frags (0..63), 64KB
  __shared__ __align__(16) float b1l[128];
  const int tid = threadIdx.x;
  {
    const uint4* s = (const uint4*)wbf;
    uint4* d = (uint4*)wlds;
    #pragma unroll
    for (int i = 0; i < 8; ++i) d[tid + i * 512] = s[tid + i * 512];
  }
  if (tid < 128) b1l[tid] = b1[tid];
  __syncthreads();

  const int lane = tid & 63, p = lane & 15, q = lane >> 4;
  const int wid = (blockIdx.x << 3) | (tid >> 6);
  const f32x4* b1f = (const f32x4*)b1l;
  const int NT = (NN + 31) >> 5;

  for (int t = wid; t < NT; t += 2048) {
    const int n0 = t * 32;
    const int rA = n0 + p, rB = n0 + 16 + p;
    const int cA = rA < NN ? rA : NN - 1, cB = rB < NN ? rB : NN - 1;
    U8 mfA[4], mfB[4];
    #pragma unroll
    for (int c = 0; c < 4; ++c) {
      float4 a0 = *(const float4*)(x + cA * 128 + 32 * c + 4 * q);
      float4 a1 = *(const float4*)(x + cA * 128 + 32 * c + 4 * q + 16);
      mfA[c].w[0] = pk2(a0.x, a0.y); mfA[c].w[1] = pk2(a0.z, a0.w);
      mfA[c].w[2] = pk2(a1.x, a1.y); mfA[c].w[3] = pk2(a1.z, a1.w);
      float4 c0 = *(const float4*)(x + cB * 128 + 32 * c + 4 * q);
      float4 c1 = *(const float4*)(x + cB * 128 + 32 * c + 4 * q + 16);
      mfB[c].w[0] = pk2(c0.x, c0.y); mfB[c].w[1] = pk2(c0.z, c0.w);
      mfB[c].w[2] = pk2(c1.x, c1.y); mfB[c].w[3] = pk2(c1.z, c1.w);
    }
    f32x4 yaA[8], yaB[8], ybA[8], ybB[8];
    #pragma unroll
    for (int n = 0; n < 8; ++n) {
      yaA[n] = (f32x4)(0.f); yaB[n] = (f32x4)(0.f);
      f32x4 b = b1f[4 * n + q];
      ybA[n] = b; ybB[n] = b;
    }
    gemm<0, 4>(wlds, lane, mfA, mfB, yaA, yaB);    // W1a (dest part)
    gemm<32, 4>(wlds, lane, mfA, mfB, ybA, ybB);   // W1b (src part, +b1)
    #pragma unroll
    for (int c = 0; c < 4; ++c) {
      *(u32x4*)(y + rA * 256 + c * 32 + q * 8)       = pack8(yaA[2*c], yaA[2*c+1]);
      *(u32x4*)(y + rA * 256 + 128 + c * 32 + q * 8) = pack8(ybA[2*c], ybA[2*c+1]);
      *(u32x4*)(y + rB * 256 + c * 32 + q * 8)       = pack8(yaB[2*c], yaB[2*c+1]);
      *(u32x4*)(y + rB * 256 + 128 + c * 32 + q * 8) = pack8(ybB[2*c], ybB[2*c+1]);
    }
  }
}

// ---- edge kernel (factorized): gather ya[dest], yb[src] frags, add+leaky,
// then GEMM2/GEMM3 + LN. W2/W3 frags (64KB) staged once; no other barriers.
__global__ __launch_bounds__(512, 2) void edge_mlp_fac(
    const int* __restrict__ ei, const float* __restrict__ b2,
    const float* __restrict__ gamma, const float* __restrict__ beta,
    const u16* __restrict__ wbf, const u16* __restrict__ y,
    float* __restrict__ out, int E) {
  __shared__ __align__(16) u16 wlds[32768];   // W2|W3 frags, 64KB
  __shared__ __align__(16) float parl[384];   // b2 | gamma | beta
  const int tid = threadIdx.x;
  {
    const uint4* s = (const uint4*)wbf;
    uint4* d = (uint4*)wlds;
    #pragma unroll
    for (int i = 0; i < 8; ++i) d[tid + i * 512] = s[tid + i * 512];
  }
  if (tid < 384) {
    int prm = tid >> 7, idx = tid & 127;
    const float* src = (prm == 0) ? b2 : (prm == 1) ? gamma : beta;
    parl[tid] = src[idx];
  }
  __syncthreads();

  const int lane = tid & 63, p = lane & 15, q = lane >> 4;
  const int wid = (blockIdx.x << 3) | (tid >> 6);
  const f32x4* pf = (const f32x4*)parl;   // b2: pf[0..31], gm: +32, bt: +64
  const int NT = E >> 5;                  // 20000
  const int NW = 4096;                    // 512 blocks x 8 waves

  int t = wid;
  int nd0, ns0, nd1, ns1;
  if (t < NT) {
    const int e0 = t * 32;
    nd0 = ei[E + e0 + p];      ns0 = ei[e0 + p];
    nd1 = ei[E + e0 + 16 + p]; ns1 = ei[e0 + 16 + p];
  }

  for (; t < NT; t += NW) {
    const int e0 = t * 32;
    U8 hfA[4], hfB[4];
    {
      u32x4 yaA[4], ybA[4], yaB[4], ybB[4];
      #pragma unroll
      for (int c = 0; c < 4; ++c) {
        yaA[c] = *(const u32x4*)(y + nd0 * 256 + c * 32 + q * 8);
        ybA[c] = *(const u32x4*)(y + ns0 * 256 + 128 + c * 32 + q * 8);
        yaB[c] = *(const u32x4*)(y + nd1 * 256 + c * 32 + q * 8);
        ybB[c] = *(const u32x4*)(y + ns1 * 256 + 128 + c * 32 + q * 8);
      }
      // prefetch next tile's indices (GEMMs below cover the latency)
      {
        const int tn = (t + NW < NT) ? t + NW : t;
        const int e0n = tn * 32;
        nd0 = ei[E + e0n + p];      ns0 = ei[e0n + p];
        nd1 = ei[E + e0n + 16 + p]; ns1 = ei[e0n + 16 + p];
      }
      #pragma unroll
      for (int c = 0; c < 4; ++c) {
        #pragma unroll
        for (int w = 0; w < 4; ++w) {
          hfA[c].w[w] = addleaky(yaA[c][w], ybA[c][w]);
          hfB[c].w[w] = addleaky(yaB[c][w], ybB[c][w]);
        }
      }
    }

    f32x4 accA[8], accB[8];
    // ---- GEMM2: init = b2 ----
    #pragma unroll
    for (int n = 0; n < 8; ++n) {
      f32x4 b = pf[4 * n + q];
      accA[n] = b; accB[n] = b;
    }
    gemm<0, 4>(wlds, lane, hfA, hfB, accA, accB);
    leaky_pack(accA, hfA);
    leaky_pack(accB, hfB);

    // ---- GEMM3: no bias ----
    #pragma unroll
    for (int n = 0; n < 8; ++n) { accA[n] = (f32x4)(0.f); accB[n] = (f32x4)(0.f); }
    gemm<32, 4>(wlds, lane, hfA, hfB, accA, accB);

    // ---- LayerNorm + store ----
    ln_store(accA, pf + 32, pf + 64, q, out + (long)(e0 + p) * 128 + 4 * q);
    ln_store(accB, pf + 32, pf + 64, q, out + (long)(e0 + 16 + p) * 128 + 4 * q);
  }
}

// ---- fallback: round-5 monolithic path (used only if ws is too small) ----
__device__ __forceinline__ void gather16(const float* __restrict__ xr0,
                                         const float* __restrict__ xr1,
                                         U8* mf) {
  #pragma unroll
  for (int c = 0; c < 4; ++c) {
    float4 a0 = *(const float4*)(xr0 + 32 * c);
    float4 a1 = *(const float4*)(xr0 + 32 * c + 16);
    mf[c].w[0] = pk2(a0.x, a0.y); mf[c].w[1] = pk2(a0.z, a0.w);
    mf[c].w[2] = pk2(a1.x, a1.y); mf[c].w[3] = pk2(a1.z, a1.w);
    float4 b0 = *(const float4*)(xr1 + 32 * c);
    float4 b1v = *(const float4*)(xr1 + 32 * c + 16);
    mf[4+c].w[0] = pk2(b0.x, b0.y); mf[4+c].w[1] = pk2(b0.z, b0.w);
    mf[4+c].w[2] = pk2(b1v.x, b1v.y); mf[4+c].w[3] = pk2(b1v.z, b1v.w);
  }
}

__global__ __launch_bounds__(512, 2) void edge_mlp_mono(
    const float* __restrict__ x, const int* __restrict__ ei,
    const float* __restrict__ b1, const float* __restrict__ b2,
    const float* __restrict__ gamma, const float* __restrict__ beta,
    const u16* __restrict__ wbf, float* __restrict__ out, int E) {
  __shared__ __align__(16) u16 wlds[65536];
  __shared__ __align__(16) float parl[512];
  const int tid = threadIdx.x;
  {
    const uint4* s = (const uint4*)wbf;
    uint4* d = (uint4*)wlds;
    #pragma unroll
    for (int i = 0; i < 16; ++i) d[tid + i * 512] = s[tid + i * 512];
  }
  if (tid < 512) {
    int prm = tid >> 7, idx = tid & 127;
    const float* src = (prm == 0) ? b1 : (prm == 1) ? b2 : (prm == 2) ? gamma : beta;
    parl[tid] = src[idx];
  }
  __syncthreads();

  const int lane = tid & 63, p = lane & 15, q = lane >> 4;
  const int wid = (blockIdx.x << 3) | (tid >> 6);
  const f32x4* pf = (const f32x4*)parl;
  const int NT = E >> 5;

  for (int t = wid; t < NT; t += 2048) {
    const int e0 = t * 32;
    const int nd0 = ei[E + e0 + p],      ns0 = ei[e0 + p];
    const int nd1 = ei[E + e0 + 16 + p], ns1 = ei[e0 + 16 + p];
    U8 mfA[8], mfB[8];
    gather16(x + (long)nd0 * 128 + 4 * q, x + (long)ns0 * 128 + 4 * q, mfA);
    gather16(x + (long)nd1 * 128 + 4 * q, x + (long)ns1 * 128 + 4 * q, mfB);

    f32x4 accA[8], accB[8];
    #pragma unroll
    for (int n = 0; n < 8; ++n) { f32x4 b = pf[4*n+q]; accA[n] = b; accB[n] = b; }
    gemm<0, 8>(wlds, lane, mfA, mfB, accA, accB);
    U8 hfA[4], hfB[4];
    leaky_pack(accA, hfA); leaky_pack(accB, hfB);
    #pragma unroll
    for (int n = 0; n < 8; ++n) { f32x4 b = pf[32+4*n+q]; accA[n] = b; accB[n] = b; }
    gemm<64, 4>(wlds, lane, hfA, hfB, accA, accB);
    leaky_pack(accA, hfA); leaky_pack(accB, hfB);
    #pragma unroll
    for (int n = 0; n < 8; ++n) { accA[n] = (f32x4)(0.f); accB[n] = (f32x4)(0.f); }
    gemm<96, 4>(wlds, lane, hfA, hfB, accA, accB);
    ln_store(accA, pf + 64, pf + 96, q, out + (long)(e0 + p) * 128 + 4 * q);
    ln_store(accB, pf + 64, pf + 96, q, out + (long)(e0 + 16 + p) * 128 + 4 * q);
  }
}

extern "C" void kernel_launch(void* const* d_in, const int* in_sizes, int n_in,
                              void* d_out, int out_size, void* d_ws, size_t ws_size,
                              hipStream_t stream) {
  const float* x     = (const float*)d_in[0];
  const int*   ei    = (const int*)d_in[1];
  const float* W1    = (const float*)d_in[2];
  const float* b1    = (const float*)d_in[3];
  const float* W2    = (const float*)d_in[4];
  const float* b2    = (const float*)d_in[5];
  const float* W3    = (const float*)d_in[6];
  const float* gamma = (const float*)d_in[7];
  const float* beta  = (const float*)d_in[8];
  const int E  = in_sizes[1] / 2;     // 640000
  const int NN = in_sizes[0] / 128;   // 50000

  const size_t npad    = ((size_t)(NN + 31) / 32) * 32;
  const size_t Y_BYTES = npad * 512;             // bf16 ya|yb per node
  const size_t NEED    = Y_BYTES + 131072;

  if (ws_size >= NEED) {
    u16* y   = (u16*)d_ws;
    u16* wbf = (u16*)((char*)d_ws + Y_BYTES);
    build_wfrag<<<256, 256, 0, stream>>>(W1, W2, W3, wbf);
    node_pre<<<256, 512, 0, stream>>>(x, b1, wbf, y, NN);
    edge_mlp_fac<<<512, 512, 0, stream>>>(ei, b2, gamma, beta, wbf + 32768, y,
                                          (float*)d_out, E);
  } else {
    u16* wbf = (u16*)d_ws;
    build_wfrag<<<256, 256, 0, stream>>>(W1, W2, W3, wbf);
    edge_mlp_mono<<<256, 512, 0, stream>>>(x, ei, b1, b2, gamma, beta, wbf,
                                           (float*)d_out, E);
  }
}